// Round 17
// baseline (189.238 us; speedup 1.0000x reference)
//
#include <hip/hip_runtime.h>

#define INF_  128
#define OUTF  256
#define LATF  128
#define OUT2  512
#define NEXP  8
#define OMEGA_ 30.0f

typedef float  f32x4  __attribute__((ext_vector_type(4)));
typedef __bf16 bf16x8 __attribute__((ext_vector_type(8)));
typedef unsigned short ushort8 __attribute__((ext_vector_type(8)));

#define PACK_THREADS (NEXP * 4 * 4 * 3 * 4 * 64)   // 98304 -> 384 blocks of 256
#define EXP_STRIDE   (4 * 4 * 3 * 4 * 512)          // 98304 ushorts = 192KB per expert
#define PH_STRIDE    6144                           // 12KB per (expert, 16-col phase)
#define GEMM_COMPUTE 1056                           // >= max ntiles 1051; 8*132
#define CAP          131072                         // per-bucket capacity (ws is ~800MB)

template<bool B> struct BoolC { static constexpr bool value = B; };

__device__ __forceinline__ unsigned short bfbits(float f) {
    unsigned int u = __builtin_bit_cast(unsigned int, f);
    return (unsigned short)((u + 0x7FFFu + ((u >> 16) & 1u)) >> 16);
}

__device__ __forceinline__ bf16x8 cvt8(f32x4 a, f32x4 b) {
    bf16x8 r;
    r[0] = (__bf16)a.x; r[1] = (__bf16)a.y; r[2] = (__bf16)a.z; r[3] = (__bf16)a.w;
    r[4] = (__bf16)b.x; r[5] = (__bf16)b.y; r[6] = (__bf16)b.z; r[7] = (__bf16)b.w;
    return r;
}

__device__ __forceinline__ f32x4 bload(const unsigned short* p) {
    const ushort4 u = *(const ushort4*)p;
    f32x4 r;
    r.x = __builtin_bit_cast(float, (unsigned int)u.x << 16);
    r.y = __builtin_bit_cast(float, (unsigned int)u.y << 16);
    r.z = __builtin_bit_cast(float, (unsigned int)u.z << 16);
    r.w = __builtin_bit_cast(float, (unsigned int)u.w << 16);
    return r;
}

// global -> LDS async, 16B per lane, linear dest (wave-uniform base)
#define GLOAD_LDS16(g, l) __builtin_amdgcn_global_load_lds( \
    (const __attribute__((address_space(1))) unsigned int*)(g), \
    (__attribute__((address_space(3))) unsigned int*)(l), 16, 0, 0)

// ---------------- fused pack + gate+scatter (grid-partitioned) ----------------
__global__ void prep_kernel(const float* __restrict__ x,
                            const float* __restrict__ gw,
                            const float* __restrict__ gb,
                            const float* __restrict__ W,
                            const float* __restrict__ Wl,
                            unsigned int* __restrict__ cur,      // 64 cursors (=counts)
                            unsigned int* __restrict__ perm,     // 64 x CAP
                            float2* __restrict__ wps,            // 64 x CAP
                            unsigned short* __restrict__ Bpk,
                            int nGate)
{
    __shared__ float sgw[INF_ * NEXP];
    __shared__ int lc[64];
    __shared__ unsigned int lbase[64];
    const int tid = threadIdx.x;

    if ((int)blockIdx.x >= nGate) {
        // ---- pack path ----
        const int t = ((int)blockIdx.x - nGate) * 256 + tid;
        if (t >= PACK_THREADS) return;
        const int l   = t & 63;
        const int ks  = (t >> 6) & 3;
        const int m3  = (t >> 8) % 3;
        const int g   = (t >> 8) / 3;
        const int nf  = g & 3, nc = (g >> 2) & 3, e = g >> 4;
        const int col = nc * 64 + nf * 16 + (l & 15);
        const int kb  = ks * 32 + (l >> 4) * 8;
        ushort8 o;
#pragma unroll
        for (int j = 0; j < 8; ++j) {
            float v;
            if (m3 == 0) v = W [((size_t)e * 128 + kb + j) * 256 + col];
            else         v = Wl[((size_t)e * 128 + kb + j) * 512 + col + (m3 == 2 ? 256 : 0)];
            o[j] = bfbits(v);
        }
        *(ushort8*)(Bpk + (size_t)t * 8) = o;
        return;
    }

    // ---- gate path (x only; latents handled inside the GEMM) ----
    ((float4*)sgw)[tid] = ((const float4*)gw)[tid];
    if (tid < 64) lc[tid] = 0;
    __syncthreads();

    const int t = blockIdx.x * 256 + tid;
    float acc[8];
#pragma unroll
    for (int e = 0; e < 8; ++e) acc[e] = gb[e];
    const float4* xr = (const float4*)(x + (size_t)t * INF_);
#pragma unroll 8
    for (int i = 0; i < 32; ++i) {
        float4 v = xr[i];
#pragma unroll
        for (int j = 0; j < 4; ++j) {
            const float xk = (&v.x)[j];
            const float4 g0 = *(const float4*)&sgw[(i * 4 + j) * 8];
            const float4 g1 = *(const float4*)&sgw[(i * 4 + j) * 8 + 4];
            acc[0] += xk * g0.x; acc[1] += xk * g0.y; acc[2] += xk * g0.z; acc[3] += xk * g0.w;
            acc[4] += xk * g1.x; acc[5] += xk * g1.y; acc[6] += xk * g1.z; acc[7] += xk * g1.w;
        }
    }
    float best = -1e30f, sec = -1e30f; int bi = 0, si = 0;
#pragma unroll
    for (int e = 0; e < 8; ++e) {
        const float v = acc[e];
        if (v > best)      { sec = best; si = bi; best = v; bi = e; }
        else if (v > sec)  { sec = v; si = e; }
    }
    const float ew  = __expf(sec - best);
    const float inv = 1.0f / (1.0f + ew);
    const float wb  = inv, wsc = ew * inv;
    int emin, emax; float wmin, wmax;
    if (bi < si) { emin = bi; wmin = wb;  emax = si; wmax = wsc; }
    else         { emin = si; wmin = wsc; emax = bi; wmax = wb;  }
    const int pid = emin * 8 + emax;

    // ---- direct scatter: LDS-aggregated reservation into capacity buckets ----
    const int p = atomicAdd(&lc[pid], 1);
    __syncthreads();
    if (tid < 64) { lbase[tid] = lc[tid] ? atomicAdd(&cur[tid], (unsigned int)lc[tid]) : 0u; }
    __syncthreads();
    const size_t q = (size_t)pid * CAP + lbase[pid] + (unsigned int)p;
    perm[q] = (unsigned int)t;
    wps[q]  = make_float2(wmin, wmax);
}

// ---------------- pair GEMM with embedded latents copy ----------------
// M=128, 4 waves, dbuf depth-1, 51KB LDS -> 3 blk/CU. Blocks bid<1024 also
// stream-copy their 64KB latents slice (1 ld + 1 st per thread per phase),
// issued in the vmcnt-exempt window after STAGE -> rides the GEMM's idle BW.
// Out-stores delayed one phase (issued after next STAGE) so in-loop waits
// never block on stores younger than ~1 phase. Order pinned by sched_barrier.
__launch_bounds__(256, 3)
__global__ void moe_gemm_kernel(const float* __restrict__ x,
                                const float* __restrict__ lat,
                                const unsigned short* __restrict__ Bpk,
                                const float* __restrict__ bias,
                                const float* __restrict__ biasl,
                                const unsigned int* __restrict__ c,   // 64 counts
                                const unsigned int* __restrict__ perm,
                                const float2* __restrict__ wps,
                                float* __restrict__ out,
                                float* __restrict__ lat_out)
{
    __shared__ __align__(16) unsigned short sB[2][2 * PH_STRIDE];   // 2 x 24KB
    __shared__ __align__(16) unsigned short sbias[6 * 256];         // 3KB bf16

    const unsigned int dd = blockIdx.x;
    const int tid  = threadIdx.x;
    // XCD-chunked bijective swizzle (1056 = 8*132)
    const unsigned int bid = (dd & 7) * (GEMM_COMPUTE / 8) + (dd >> 3);
    const int lane = tid & 63;

    // ---- in-wave bucket lookup from counts (each wave redundantly) ----
    const unsigned int n_l  = c[lane];
    const unsigned int nt_l = (n_l + 127) >> 7;
    unsigned int ts = nt_l;
#pragma unroll
    for (int s = 1; s < 64; s <<= 1) {
        unsigned int tt = __shfl_up(ts, s);
        if (lane >= s) ts += tt;
    }
    const unsigned int texcl  = ts - nt_l;
    const unsigned int ntiles = __shfl(ts, 63);   // >= 1024 always (sum cnt = N)
    if (bid >= ntiles) return;                    // uniform exit before barriers
    const unsigned long long mk = __ballot(bid >= texcl);   // monotone prefix
    const int pid  = __popcll(mk) - 1;
    const int tile = (int)(bid - __shfl(texcl, pid));
    const unsigned int cn = __shfl(n_l, pid);
    const int emin = pid >> 3, emax = pid & 7;
    const int rows = min(128, (int)(cn - (unsigned int)tile * 128u));
    const unsigned int* permS = perm + (size_t)pid * CAP + (size_t)tile * 128u;
    const float2* wS = wps + (size_t)pid * CAP + (size_t)tile * 128u;

    const int w    = tid >> 6;           // 4 waves; wave owns rows w*32..w*32+31
    const int lrow = lane & 15;
    const int lgrp = lane >> 4;
    const int half = tid >> 7;           // 0: expert emin, 1: expert emax staging
    const int wh   = (tid >> 6) & 1;     // wave-within-half
    const int t7   = tid & 127;

    // ---- embedded latents-copy slice (bid<1024 <= ntiles: always live) ----
    const bool docp = bid < 1024u;
    const f32x4* cps = (const f32x4*)lat     + ((size_t)bid << 12) + tid;
    f32x4*       cpd = (f32x4*)lat_out       + ((size_t)bid << 12) + tid;
    f32x4 cpv;

    // ---- A gather -> registers (MFMA layout), f32 -> bf16, non-temporal ----
    const int r0 = w * 32 + lrow, r1 = r0 + 16;
    const int t0 = (int)permS[min(r0, rows - 1)];
    const int t1 = (int)permS[min(r1, rows - 1)];
    const float2 w0 = wS[min(r0, rows - 1)];
    const float2 w1 = wS[min(r1, rows - 1)];
    bf16x8 ax[2][4], al[2][4];
    {
        const float* x0 = x   + (size_t)t0 * INF_;
        const float* x1 = x   + (size_t)t1 * INF_;
        const float* l0 = lat + (size_t)t0 * LATF;
        const float* l1 = lat + (size_t)t1 * LATF;
#pragma unroll
        for (int ks = 0; ks < 4; ++ks) {
            const int kb = ks * 32 + lgrp * 8;
            ax[0][ks] = cvt8(__builtin_nontemporal_load((const f32x4*)(x0 + kb)),
                             __builtin_nontemporal_load((const f32x4*)(x0 + kb + 4)));
            ax[1][ks] = cvt8(__builtin_nontemporal_load((const f32x4*)(x1 + kb)),
                             __builtin_nontemporal_load((const f32x4*)(x1 + kb + 4)));
            al[0][ks] = cvt8(__builtin_nontemporal_load((const f32x4*)(l0 + kb)),
                             __builtin_nontemporal_load((const f32x4*)(l0 + kb + 4)));
            al[1][ks] = cvt8(__builtin_nontemporal_load((const f32x4*)(l1 + kb)),
                             __builtin_nontemporal_load((const f32x4*)(l1 + kb + 4)));
        }
    }

    const unsigned short* B0 = Bpk + (size_t)emin * EXP_STRIDE;
    const unsigned short* B1 = Bpk + (size_t)emax * EXP_STRIDE;
    const unsigned short* Bh = half ? B1 : B0;

    // ---- bias -> LDS as bf16: seg 0=b0h 1=b1h 2=b0s 3=b0f 4=b1s 5=b1f ----
    {
        const int i4 = (tid & 63) * 4;
        const int sg = tid >> 6;                 // 0..3
#pragma unroll
        for (int rep = 0; rep < 2; ++rep) {
            const int seg = sg + rep * 4;
            if (seg < 6) {
                const float* bsrc =
                    (seg == 0) ? bias  + emin * OUTF :
                    (seg == 1) ? bias  + emax * OUTF :
                    (seg == 2) ? biasl + emin * OUT2 :
                    (seg == 3) ? biasl + emin * OUT2 + 256 :
                    (seg == 4) ? biasl + emax * OUT2 :
                                 biasl + emax * OUT2 + 256;
                const f32x4 v = *(const f32x4*)(bsrc + i4);
                ushort4 u;
                u.x = bfbits(v.x); u.y = bfbits(v.y); u.z = bfbits(v.z); u.w = bfbits(v.w);
                *(ushort4*)&sbias[seg * 256 + i4] = u;
            }
        }
    }

    // stage phase ph's 24KB into buffer buf (6 loads/thread; 128 thr per expert half)
    auto STAGE = [&](int ph, int buf) {
        const unsigned short* src = Bh + (size_t)ph * PH_STRIDE + (size_t)t7 * 8;
        unsigned short* dst = &sB[buf][half * PH_STRIDE + wh * 512];
#pragma unroll
        for (int r = 0; r < 6; ++r)
            GLOAD_LDS16(src + r * 1024, dst + r * 1024);
    };

    f32x4 acc[2][3][2];   // [expert][mat][mf]; zero-init, bias added in epilogue
    auto COMPUTE = [&](int buf) {
#pragma unroll
        for (int ex = 0; ex < 2; ++ex)
#pragma unroll
            for (int m = 0; m < 3; ++m)
#pragma unroll
                for (int mf = 0; mf < 2; ++mf) acc[ex][m][mf] = (f32x4)0.0f;
#pragma unroll
        for (int ex = 0; ex < 2; ++ex) {
#pragma unroll
            for (int m = 0; m < 3; ++m) {
                bf16x8 bb[4];
#pragma unroll
                for (int ks = 0; ks < 4; ++ks)
                    bb[ks] = *(const bf16x8*)&sB[buf][ex * PH_STRIDE + (m * 4 + ks) * 512 + lane * 8];
#pragma unroll
                for (int ks = 0; ks < 4; ++ks) {
#pragma unroll
                    for (int mf = 0; mf < 2; ++mf) {
                        const bf16x8 a = (m == 0) ? ax[mf][ks] : al[mf][ks];
                        // swapped operands -> transposed C: row=outcol, col=token
                        acc[ex][m][mf] = __builtin_amdgcn_mfma_f32_16x16x32_bf16(bb[ks], a, acc[ex][m][mf], 0, 0, 0);
                    }
                }
            }
        }
    };

    f32x4 vsave[2];
    auto EPI_CALC = [&](int ph) {
        const int cb = ph * 16 + lgrp * 4;
        const f32x4 b0h = bload(&sbias[0 * 256 + cb]);
        const f32x4 b1h = bload(&sbias[1 * 256 + cb]);
        const f32x4 b0s = bload(&sbias[2 * 256 + cb]);
        const f32x4 b0f = bload(&sbias[3 * 256 + cb]);
        const f32x4 b1s = bload(&sbias[4 * 256 + cb]);
        const f32x4 b1f = bload(&sbias[5 * 256 + cb]);
#pragma unroll
        for (int mf = 0; mf < 2; ++mf) {
            const float wmn = mf ? w1.x : w0.x;
            const float wmx = mf ? w1.y : w0.y;
            f32x4 v;
#pragma unroll
            for (int j = 0; j < 4; ++j) {
                const float h0 = acc[0][0][mf][j] + b0h[j];
                const float s0 = acc[0][1][mf][j] + b0s[j];
                const float f0 = acc[0][2][mf][j] + b0f[j];
                const float h1 = acc[1][0][mf][j] + b1h[j];
                const float s1 = acc[1][1][mf][j] + b1s[j];
                const float f1 = acc[1][2][mf][j] + b1f[j];
                v[j] = wmn * __sinf(OMEGA_ * h0 * s0 + f0)
                     + wmx * __sinf(OMEGA_ * h1 * s1 + f1);
            }
            vsave[mf] = v;
        }
    };
    auto EPI_STORE = [&](int ph, bool guard) {
        const int cb = ph * 16 + lgrp * 4;
#pragma unroll
        for (int mf = 0; mf < 2; ++mf) {
            if (guard && ((mf ? r1 : r0) >= rows)) continue;
            __builtin_nontemporal_store(vsave[mf],
                (f32x4*)(out + (size_t)(mf ? t1 : t0) * OUTF + cb));
        }
    };

    // ---- prologue: bias ds_writes + S0; drain both counters, barrier ----
    STAGE(0, 0);
    asm volatile("s_waitcnt vmcnt(0) lgkmcnt(0)" ::: "memory");
    __builtin_amdgcn_s_barrier();
    __builtin_amdgcn_sched_barrier(0);

    if (rows == 128) {
        auto fastloop = [&](auto DC) {
            constexpr bool CP = decltype(DC)::value;
#pragma unroll 1
            for (int ph = 0; ph < 16; ++ph) {
                const int buf = ph & 1;
                if (ph < 15) STAGE(ph + 1, buf ^ 1);
                __builtin_amdgcn_sched_barrier(0);   // pin: S before exempt ops
                if constexpr (CP) {
                    if (ph > 0) __builtin_nontemporal_store(cpv, cpd + (ph - 1) * 256);
                    cpv = __builtin_nontemporal_load(cps + ph * 256);
                }
                if (ph > 0) EPI_STORE(ph - 1, false);
                __builtin_amdgcn_sched_barrier(0);   // pin: exempt ops before compute
                COMPUTE(buf);
                EPI_CALC(ph);
                __builtin_amdgcn_sched_barrier(0);
                if (ph < 15) {
                    // exempt (issued after S(ph+1)): CP: cpst+cpld+2 out-st = 4 (ph>0), 1 (ph==0)
                    //                               !CP: 2 out-st (ph>0), 0 (ph==0)
                    if (ph == 0) {
                        if constexpr (CP) asm volatile("s_waitcnt vmcnt(1)" ::: "memory");
                        else              asm volatile("s_waitcnt vmcnt(0)" ::: "memory");
                    } else {
                        if constexpr (CP) asm volatile("s_waitcnt vmcnt(4)" ::: "memory");
                        else              asm volatile("s_waitcnt vmcnt(2)" ::: "memory");
                    }
                    __builtin_amdgcn_s_barrier();
                    __builtin_amdgcn_sched_barrier(0);
                }
            }
            if constexpr (CP) __builtin_nontemporal_store(cpv, cpd + 15 * 256);
            EPI_STORE(15, false);
        };
        if (docp) fastloop(BoolC<true>{});
        else      fastloop(BoolC<false>{});
    } else {
        // ---- slow path (partial tile, <=27 tiles): full drain per phase ----
#pragma unroll 1
        for (int ph = 0; ph < 16; ++ph) {
            const int buf = ph & 1;
            if (ph > 0) {
                STAGE(ph, buf);
                asm volatile("s_waitcnt vmcnt(0)" ::: "memory");
                __builtin_amdgcn_s_barrier();
                __builtin_amdgcn_sched_barrier(0);
            }
            if (docp) {
                if (ph > 0) __builtin_nontemporal_store(cpv, cpd + (ph - 1) * 256);
                cpv = __builtin_nontemporal_load(cps + ph * 256);
            }
            COMPUTE(buf);
            EPI_CALC(ph);
            EPI_STORE(ph, true);
            __builtin_amdgcn_s_barrier();
            __builtin_amdgcn_sched_barrier(0);
        }
        if (docp) __builtin_nontemporal_store(cpv, cpd + 15 * 256);
    }
}

extern "C" void kernel_launch(void* const* d_in, const int* in_sizes, int n_in,
                              void* d_out, int out_size, void* d_ws, size_t ws_size,
                              hipStream_t stream)
{
    const float* x   = (const float*)d_in[0];
    const float* lat = (const float*)d_in[1];
    const float* gw  = (const float*)d_in[2];
    const float* gb  = (const float*)d_in[3];
    const float* W   = (const float*)d_in[4];
    const float* b   = (const float*)d_in[5];
    const float* Wl  = (const float*)d_in[6];
    const float* bl  = (const float*)d_in[7];
    float* out = (float*)d_out;
    const int N = in_sizes[0] / INF_;   // 131072

    char* ws = (char*)d_ws;
    unsigned int*   cur  = (unsigned int*)ws;                         // 64 cursors (=counts)
    unsigned short* Bpk  = (unsigned short*)(ws + 4096);              // 1.5MB
    unsigned int*   perm = (unsigned int*)(ws + (4096 + 2 * (size_t)EXP_STRIDE * NEXP + 4096));
    float2*         wps  = (float2*)((char*)perm + (size_t)64 * CAP * sizeof(unsigned int));

    (void)hipMemsetAsync(cur, 0, 256, stream);      // zero cursors only

    const int nGate = N / 256;                      // 512
    prep_kernel<<<dim3(nGate + PACK_THREADS / 256), 256, 0, stream>>>(
        x, gw, gb, W, Wl, cur, perm, wps, Bpk, nGate);

    moe_gemm_kernel<<<dim3(GEMM_COMPUTE), 256, 0, stream>>>(
        x, lat, Bpk, b, bl, cur, perm, wps, out, out + (size_t)N * OUTF);
}

// Round 18
// 161.066 us; speedup vs baseline: 1.1749x; 1.1749x over previous
//
#include <hip/hip_runtime.h>

#define INF_  128
#define OUTF  256
#define LATF  128
#define OUT2  512
#define NEXP  8
#define OMEGA_ 30.0f

typedef float  f32x4  __attribute__((ext_vector_type(4)));
typedef __bf16 bf16x8 __attribute__((ext_vector_type(8)));
typedef unsigned short ushort8 __attribute__((ext_vector_type(8)));

#define PACK_THREADS (NEXP * 4 * 4 * 3 * 4 * 64)   // 98304 -> 384 blocks of 256
#define EXP_STRIDE   (4 * 4 * 3 * 4 * 512)          // 98304 ushorts = 192KB per expert
#define PH_STRIDE    6144                           // 12KB per (expert, 16-col phase)
#define GEMM_COMPUTE 1056                           // >= max ntiles 1051; 8*132
#define COPY_BLOCKS  512                            // latents copiers, grid tail (R13)
#define GEMM_GRID    (GEMM_COMPUTE + COPY_BLOCKS)
#define CAP          131072                         // per-bucket capacity (ws ~800MB)

__device__ __forceinline__ unsigned short bfbits(float f) {
    unsigned int u = __builtin_bit_cast(unsigned int, f);
    return (unsigned short)((u + 0x7FFFu + ((u >> 16) & 1u)) >> 16);
}

__device__ __forceinline__ bf16x8 cvt8(f32x4 a, f32x4 b) {
    bf16x8 r;
    r[0] = (__bf16)a.x; r[1] = (__bf16)a.y; r[2] = (__bf16)a.z; r[3] = (__bf16)a.w;
    r[4] = (__bf16)b.x; r[5] = (__bf16)b.y; r[6] = (__bf16)b.z; r[7] = (__bf16)b.w;
    return r;
}

__device__ __forceinline__ f32x4 bload(const unsigned short* p) {
    const ushort4 u = *(const ushort4*)p;
    f32x4 r;
    r.x = __builtin_bit_cast(float, (unsigned int)u.x << 16);
    r.y = __builtin_bit_cast(float, (unsigned int)u.y << 16);
    r.z = __builtin_bit_cast(float, (unsigned int)u.z << 16);
    r.w = __builtin_bit_cast(float, (unsigned int)u.w << 16);
    return r;
}

// ---------------- fused pack + gate+scatter (grid-partitioned) ----------------
__global__ void prep_kernel(const float* __restrict__ x,
                            const float* __restrict__ gw,
                            const float* __restrict__ gb,
                            const float* __restrict__ W,
                            const float* __restrict__ Wl,
                            unsigned int* __restrict__ cur,      // 64 cursors (=counts)
                            unsigned int* __restrict__ perm,     // 64 x CAP
                            float2* __restrict__ wps,            // 64 x CAP
                            unsigned short* __restrict__ Bpk,
                            int nGate)
{
    __shared__ float sgw[INF_ * NEXP];
    __shared__ int lc[64];
    __shared__ unsigned int lbase[64];
    const int tid = threadIdx.x;

    if ((int)blockIdx.x >= nGate) {
        // ---- pack path ----
        const int t = ((int)blockIdx.x - nGate) * 256 + tid;
        if (t >= PACK_THREADS) return;
        const int l   = t & 63;
        const int ks  = (t >> 6) & 3;
        const int m3  = (t >> 8) % 3;
        const int g   = (t >> 8) / 3;
        const int nf  = g & 3, nc = (g >> 2) & 3, e = g >> 4;
        const int col = nc * 64 + nf * 16 + (l & 15);
        const int kb  = ks * 32 + (l >> 4) * 8;
        ushort8 o;
#pragma unroll
        for (int j = 0; j < 8; ++j) {
            float v;
            if (m3 == 0) v = W [((size_t)e * 128 + kb + j) * 256 + col];
            else         v = Wl[((size_t)e * 128 + kb + j) * 512 + col + (m3 == 2 ? 256 : 0)];
            o[j] = bfbits(v);
        }
        *(ushort8*)(Bpk + (size_t)t * 8) = o;
        return;
    }

    // ---- gate path (x only; latents handled by GEMM copier blocks) ----
    ((float4*)sgw)[tid] = ((const float4*)gw)[tid];
    if (tid < 64) lc[tid] = 0;
    __syncthreads();

    const int t = blockIdx.x * 256 + tid;
    float acc[8];
#pragma unroll
    for (int e = 0; e < 8; ++e) acc[e] = gb[e];
    const float4* xr = (const float4*)(x + (size_t)t * INF_);
#pragma unroll 8
    for (int i = 0; i < 32; ++i) {
        float4 v = xr[i];
#pragma unroll
        for (int j = 0; j < 4; ++j) {
            const float xk = (&v.x)[j];
            const float4 g0 = *(const float4*)&sgw[(i * 4 + j) * 8];
            const float4 g1 = *(const float4*)&sgw[(i * 4 + j) * 8 + 4];
            acc[0] += xk * g0.x; acc[1] += xk * g0.y; acc[2] += xk * g0.z; acc[3] += xk * g0.w;
            acc[4] += xk * g1.x; acc[5] += xk * g1.y; acc[6] += xk * g1.z; acc[7] += xk * g1.w;
        }
    }
    float best = -1e30f, sec = -1e30f; int bi = 0, si = 0;
#pragma unroll
    for (int e = 0; e < 8; ++e) {
        const float v = acc[e];
        if (v > best)      { sec = best; si = bi; best = v; bi = e; }
        else if (v > sec)  { sec = v; si = e; }
    }
    const float ew  = __expf(sec - best);
    const float inv = 1.0f / (1.0f + ew);
    const float wb  = inv, wsc = ew * inv;
    int emin, emax; float wmin, wmax;
    if (bi < si) { emin = bi; wmin = wb;  emax = si; wmax = wsc; }
    else         { emin = si; wmin = wsc; emax = bi; wmax = wb;  }
    const int pid = emin * 8 + emax;

    // ---- direct scatter: LDS-aggregated reservation into capacity buckets ----
    const int p = atomicAdd(&lc[pid], 1);
    __syncthreads();
    if (tid < 64) { lbase[tid] = lc[tid] ? atomicAdd(&cur[tid], (unsigned int)lc[tid]) : 0u; }
    __syncthreads();
    const size_t q = (size_t)pid * CAP + lbase[pid] + (unsigned int)p;
    perm[q] = (unsigned int)t;
    wps[q]  = make_float2(wmin, wmax);
}

// ---------------- pair GEMM: register-direct B, ZERO phase barriers ----------------
// M=128, 4 waves. B fragments stream straight from the XCD-local L2-resident
// Bpk into a rotating 3-slot register pipeline (depth-2 group prefetch, all
// slot indices compile-time). No LDS-B, no s_barrier in the loop, no manual
// vmcnt -- every wave runs free; compiler inserts exact waitcnts. One barrier
// total (bias LDS). Copier blocks at grid tail (proven R13 placement).
__launch_bounds__(256, 2)
__global__ void moe_gemm_kernel(const float* __restrict__ x,
                                const float* __restrict__ lat,
                                const unsigned short* __restrict__ Bpk,
                                const float* __restrict__ bias,
                                const float* __restrict__ biasl,
                                const unsigned int* __restrict__ c,   // 64 counts
                                const unsigned int* __restrict__ perm,
                                const float2* __restrict__ wps,
                                float* __restrict__ out,
                                float* __restrict__ lat_out)
{
    __shared__ __align__(16) unsigned short sbias[6 * 256];   // 3KB bf16

    const unsigned int dd = blockIdx.x;
    const int tid  = threadIdx.x;

    if (dd >= GEMM_COMPUTE) {
        // ---- latents copier tail: 512 blocks x 32 f32x4/thread ----
        const int cb = (int)dd - GEMM_COMPUTE;
        const f32x4* src = (const f32x4*)lat + (size_t)cb * 8192;
        f32x4*       dst = (f32x4*)lat_out   + (size_t)cb * 8192;
#pragma unroll
        for (int i = 0; i < 32; ++i) {
            f32x4 v = __builtin_nontemporal_load(&src[tid + i * 256]);
            __builtin_nontemporal_store(v, &dst[tid + i * 256]);
        }
        return;
    }

    // XCD-chunked bijective swizzle (1056 = 8*132): keeps Bpk L2-resident/XCD
    const unsigned int bid = (dd & 7) * (GEMM_COMPUTE / 8) + (dd >> 3);
    const int lane = tid & 63;

    // ---- in-wave bucket lookup from counts ----
    const unsigned int n_l  = c[lane];
    const unsigned int nt_l = (n_l + 127) >> 7;
    unsigned int ts = nt_l;
#pragma unroll
    for (int s = 1; s < 64; s <<= 1) {
        unsigned int tt = __shfl_up(ts, s);
        if (lane >= s) ts += tt;
    }
    const unsigned int texcl  = ts - nt_l;
    const unsigned int ntiles = __shfl(ts, 63);
    if (bid >= ntiles) return;                    // uniform exit before barrier
    const unsigned long long mk = __ballot(bid >= texcl);
    const int pid  = __popcll(mk) - 1;
    const int tile = (int)(bid - __shfl(texcl, pid));
    const unsigned int cn = __shfl(n_l, pid);
    const int emin = pid >> 3, emax = pid & 7;
    const int rows = min(128, (int)(cn - (unsigned int)tile * 128u));
    const unsigned int* permS = perm + (size_t)pid * CAP + (size_t)tile * 128u;
    const float2* wS = wps + (size_t)pid * CAP + (size_t)tile * 128u;

    const int w    = tid >> 6;           // 4 waves; wave owns rows w*32..w*32+31
    const int lrow = lane & 15;
    const int lgrp = lane >> 4;

    // ---- A gather -> registers (MFMA layout), f32 -> bf16, non-temporal ----
    const int r0 = w * 32 + lrow, r1 = r0 + 16;
    const int t0 = (int)permS[min(r0, rows - 1)];
    const int t1 = (int)permS[min(r1, rows - 1)];
    const float2 w0 = wS[min(r0, rows - 1)];
    const float2 w1 = wS[min(r1, rows - 1)];
    bf16x8 ax[2][4], al[2][4];
    {
        const float* x0 = x   + (size_t)t0 * INF_;
        const float* x1 = x   + (size_t)t1 * INF_;
        const float* l0 = lat + (size_t)t0 * LATF;
        const float* l1 = lat + (size_t)t1 * LATF;
#pragma unroll
        for (int ks = 0; ks < 4; ++ks) {
            const int kb = ks * 32 + lgrp * 8;
            ax[0][ks] = cvt8(__builtin_nontemporal_load((const f32x4*)(x0 + kb)),
                             __builtin_nontemporal_load((const f32x4*)(x0 + kb + 4)));
            ax[1][ks] = cvt8(__builtin_nontemporal_load((const f32x4*)(x1 + kb)),
                             __builtin_nontemporal_load((const f32x4*)(x1 + kb + 4)));
            al[0][ks] = cvt8(__builtin_nontemporal_load((const f32x4*)(l0 + kb)),
                             __builtin_nontemporal_load((const f32x4*)(l0 + kb + 4)));
            al[1][ks] = cvt8(__builtin_nontemporal_load((const f32x4*)(l1 + kb)),
                             __builtin_nontemporal_load((const f32x4*)(l1 + kb + 4)));
        }
    }

    // ---- bias -> LDS as bf16: seg 0=b0h 1=b1h 2=b0s 3=b0f 4=b1s 5=b1f ----
    {
        const int i4 = (tid & 63) * 4;
        const int sg = tid >> 6;                 // 0..3
#pragma unroll
        for (int rep = 0; rep < 2; ++rep) {
            const int seg = sg + rep * 4;
            if (seg < 6) {
                const float* bsrc =
                    (seg == 0) ? bias  + emin * OUTF :
                    (seg == 1) ? bias  + emax * OUTF :
                    (seg == 2) ? biasl + emin * OUT2 :
                    (seg == 3) ? biasl + emin * OUT2 + 256 :
                    (seg == 4) ? biasl + emax * OUT2 :
                                 biasl + emax * OUT2 + 256;
                const f32x4 v = *(const f32x4*)(bsrc + i4);
                ushort4 u;
                u.x = bfbits(v.x); u.y = bfbits(v.y); u.z = bfbits(v.z); u.w = bfbits(v.w);
                *(ushort4*)&sbias[seg * 256 + i4] = u;
            }
        }
    }
    asm volatile("s_waitcnt lgkmcnt(0)" ::: "memory");
    __builtin_amdgcn_s_barrier();               // the ONLY block-wide barrier

    // ---- B stream: per-lane base pointers into fragment-ordered Bpk ----
    const unsigned short* Bb0 = Bpk + (size_t)emin * EXP_STRIDE + lane * 8;
    const unsigned short* Bb1 = Bpk + (size_t)emax * EXP_STRIDE + lane * 8;

    bf16x8 bfr[3][4];     // rotating 3-slot pipeline; slot = group%3 (static)
    f32x4  acc[2][3][2];  // [expert][mat][mf]; bias folded into init

    auto LOADG = [&](int ph, int g, int slot) {
        const unsigned short* base = (g >= 3 ? Bb1 : Bb0)
                                   + (size_t)ph * PH_STRIDE + (g % 3) * 2048;
#pragma unroll
        for (int ks = 0; ks < 4; ++ks)
            bfr[slot][ks] = *(const bf16x8*)(base + ks * 512);
    };
    auto MMAG = [&](int g) {
        const int ex = g / 3, m = g % 3;
#pragma unroll
        for (int ks = 0; ks < 4; ++ks)
#pragma unroll
            for (int mf = 0; mf < 2; ++mf) {
                const bf16x8 a = (m == 0) ? ax[mf][ks] : al[mf][ks];
                // swapped operands -> transposed C: row=outcol, col=token
                acc[ex][m][mf] = __builtin_amdgcn_mfma_f32_16x16x32_bf16(
                                     bfr[g % 3][ks], a, acc[ex][m][mf], 0, 0, 0);
            }
    };

    // prologue: groups 0,1 of phase 0 in flight
    LOADG(0, 0, 0);
    LOADG(0, 1, 1);

#pragma unroll 1
    for (int ph = 0; ph < 16; ++ph) {
        const int cb = ph * 16 + lgrp * 4;
        // acc init = bias (dtype-matched to epilogue formula)
        {
            const f32x4 b0h = bload(&sbias[0 * 256 + cb]);
            const f32x4 b1h = bload(&sbias[1 * 256 + cb]);
            const f32x4 b0s = bload(&sbias[2 * 256 + cb]);
            const f32x4 b0f = bload(&sbias[3 * 256 + cb]);
            const f32x4 b1s = bload(&sbias[4 * 256 + cb]);
            const f32x4 b1f = bload(&sbias[5 * 256 + cb]);
#pragma unroll
            for (int mf = 0; mf < 2; ++mf) {
                acc[0][0][mf] = b0h; acc[0][1][mf] = b0s; acc[0][2][mf] = b0f;
                acc[1][0][mf] = b1h; acc[1][1][mf] = b1s; acc[1][2][mf] = b1f;
            }
        }
        // 6 groups, depth-2 register prefetch, no barriers
#pragma unroll
        for (int g = 0; g < 6; ++g) {
            if (g < 4)        LOADG(ph, g + 2, (g + 2) % 3);
            else if (ph < 15) LOADG(ph + 1, g - 4, (g - 4) % 3);
            MMAG(g);
        }
        // fused epilogue: out = wmin*sin(30*h0*s0+f0) + wmax*sin(30*h1*s1+f1)
#pragma unroll
        for (int mf = 0; mf < 2; ++mf) {
            const int rr = mf ? r1 : r0;
            if (rr < rows) {
                const float wmn = mf ? w1.x : w0.x;
                const float wmx = mf ? w1.y : w0.y;
                f32x4 v;
#pragma unroll
                for (int j = 0; j < 4; ++j) {
                    const float h0 = acc[0][0][mf][j];
                    const float s0 = acc[0][1][mf][j];
                    const float f0 = acc[0][2][mf][j];
                    const float h1 = acc[1][0][mf][j];
                    const float s1 = acc[1][1][mf][j];
                    const float f1 = acc[1][2][mf][j];
                    v[j] = wmn * __sinf(OMEGA_ * h0 * s0 + f0)
                         + wmx * __sinf(OMEGA_ * h1 * s1 + f1);
                }
                __builtin_nontemporal_store(v,
                    (f32x4*)(out + (size_t)(mf ? t1 : t0) * OUTF + cb));
            }
        }
    }
}

extern "C" void kernel_launch(void* const* d_in, const int* in_sizes, int n_in,
                              void* d_out, int out_size, void* d_ws, size_t ws_size,
                              hipStream_t stream)
{
    const float* x   = (const float*)d_in[0];
    const float* lat = (const float*)d_in[1];
    const float* gw  = (const float*)d_in[2];
    const float* gb  = (const float*)d_in[3];
    const float* W   = (const float*)d_in[4];
    const float* b   = (const float*)d_in[5];
    const float* Wl  = (const float*)d_in[6];
    const float* bl  = (const float*)d_in[7];
    float* out = (float*)d_out;
    const int N = in_sizes[0] / INF_;   // 131072

    char* ws = (char*)d_ws;
    unsigned int*   cur  = (unsigned int*)ws;                         // 64 cursors (=counts)
    unsigned short* Bpk  = (unsigned short*)(ws + 4096);              // 1.5MB
    unsigned int*   perm = (unsigned int*)(ws + (4096 + 2 * (size_t)EXP_STRIDE * NEXP + 4096));
    float2*         wps  = (float2*)((char*)perm + (size_t)64 * CAP * sizeof(unsigned int));

    (void)hipMemsetAsync(cur, 0, 256, stream);      // zero cursors only

    const int nGate = N / 256;                      // 512
    prep_kernel<<<dim3(nGate + PACK_THREADS / 256), 256, 0, stream>>>(
        x, gw, gb, W, Wl, cur, perm, wps, Bpk, nGate);

    moe_gemm_kernel<<<dim3(GEMM_GRID), 256, 0, stream>>>(
        x, lat, Bpk, b, bl, cur, perm, wps, out, out + (size_t)N * OUTF);
}

// Round 19
// 145.545 us; speedup vs baseline: 1.3002x; 1.1066x over previous
//
#include <hip/hip_runtime.h>

#define INF_  128
#define OUTF  256
#define LATF  128
#define OUT2  512
#define NEXP  8
#define OMEGA_ 30.0f

typedef float  f32x4  __attribute__((ext_vector_type(4)));
typedef __bf16 bf16x8 __attribute__((ext_vector_type(8)));
typedef unsigned short ushort8 __attribute__((ext_vector_type(8)));

#define PACK_THREADS (NEXP * 4 * 4 * 3 * 4 * 64)   // 98304 -> 384 blocks of 256
#define EXP_STRIDE   (4 * 4 * 3 * 4 * 512)          // 98304 ushorts = 192KB per expert
#define PH_STRIDE    6144                           // 12KB per (expert, 16-col phase)
#define GEMM_COMPUTE 1056                           // >= max ntiles 1051; 8*132
#define COPY_BLOCKS  512                            // latents copiers, grid tail
#define GEMM_GRID    (GEMM_COMPUTE + COPY_BLOCKS)
#define CAP          131072                         // per-bucket capacity (ws ~800MB)

__device__ __forceinline__ unsigned short bfbits(float f) {
    unsigned int u = __builtin_bit_cast(unsigned int, f);
    return (unsigned short)((u + 0x7FFFu + ((u >> 16) & 1u)) >> 16);
}

__device__ __forceinline__ bf16x8 cvt8(f32x4 a, f32x4 b) {
    bf16x8 r;
    r[0] = (__bf16)a.x; r[1] = (__bf16)a.y; r[2] = (__bf16)a.z; r[3] = (__bf16)a.w;
    r[4] = (__bf16)b.x; r[5] = (__bf16)b.y; r[6] = (__bf16)b.z; r[7] = (__bf16)b.w;
    return r;
}

__device__ __forceinline__ f32x4 bload(const unsigned short* p) {
    const ushort4 u = *(const ushort4*)p;
    f32x4 r;
    r.x = __builtin_bit_cast(float, (unsigned int)u.x << 16);
    r.y = __builtin_bit_cast(float, (unsigned int)u.y << 16);
    r.z = __builtin_bit_cast(float, (unsigned int)u.z << 16);
    r.w = __builtin_bit_cast(float, (unsigned int)u.w << 16);
    return r;
}

// global -> LDS async, 16B per lane, linear dest (wave-uniform base)
#define GLOAD_LDS16(g, l) __builtin_amdgcn_global_load_lds( \
    (const __attribute__((address_space(1))) unsigned int*)(g), \
    (__attribute__((address_space(3))) unsigned int*)(l), 16, 0, 0)

// ---------------- fused pack + gate+scatter (grid-partitioned) ----------------
__global__ void prep_kernel(const float* __restrict__ x,
                            const float* __restrict__ gw,
                            const float* __restrict__ gb,
                            const float* __restrict__ W,
                            const float* __restrict__ Wl,
                            unsigned int* __restrict__ cur,      // 64 cursors (=counts)
                            unsigned int* __restrict__ perm,     // 64 x CAP
                            float2* __restrict__ wps,            // 64 x CAP
                            unsigned short* __restrict__ Bpk,
                            int nGate)
{
    __shared__ float sgw[INF_ * NEXP];
    __shared__ int lc[64];
    __shared__ unsigned int lbase[64];
    const int tid = threadIdx.x;

    if ((int)blockIdx.x >= nGate) {
        // ---- pack path ----
        const int t = ((int)blockIdx.x - nGate) * 256 + tid;
        if (t >= PACK_THREADS) return;
        const int l   = t & 63;
        const int ks  = (t >> 6) & 3;
        const int m3  = (t >> 8) % 3;
        const int g   = (t >> 8) / 3;
        const int nf  = g & 3, nc = (g >> 2) & 3, e = g >> 4;
        const int col = nc * 64 + nf * 16 + (l & 15);
        const int kb  = ks * 32 + (l >> 4) * 8;
        ushort8 o;
#pragma unroll
        for (int j = 0; j < 8; ++j) {
            float v;
            if (m3 == 0) v = W [((size_t)e * 128 + kb + j) * 256 + col];
            else         v = Wl[((size_t)e * 128 + kb + j) * 512 + col + (m3 == 2 ? 256 : 0)];
            o[j] = bfbits(v);
        }
        *(ushort8*)(Bpk + (size_t)t * 8) = o;
        return;
    }

    // ---- gate path (x only; latents handled by GEMM copier blocks) ----
    ((float4*)sgw)[tid] = ((const float4*)gw)[tid];
    if (tid < 64) lc[tid] = 0;
    __syncthreads();

    const int t = blockIdx.x * 256 + tid;
    float acc[8];
#pragma unroll
    for (int e = 0; e < 8; ++e) acc[e] = gb[e];
    const float4* xr = (const float4*)(x + (size_t)t * INF_);
#pragma unroll 8
    for (int i = 0; i < 32; ++i) {
        float4 v = xr[i];
#pragma unroll
        for (int j = 0; j < 4; ++j) {
            const float xk = (&v.x)[j];
            const float4 g0 = *(const float4*)&sgw[(i * 4 + j) * 8];
            const float4 g1 = *(const float4*)&sgw[(i * 4 + j) * 8 + 4];
            acc[0] += xk * g0.x; acc[1] += xk * g0.y; acc[2] += xk * g0.z; acc[3] += xk * g0.w;
            acc[4] += xk * g1.x; acc[5] += xk * g1.y; acc[6] += xk * g1.z; acc[7] += xk * g1.w;
        }
    }
    float best = -1e30f, sec = -1e30f; int bi = 0, si = 0;
#pragma unroll
    for (int e = 0; e < 8; ++e) {
        const float v = acc[e];
        if (v > best)      { sec = best; si = bi; best = v; bi = e; }
        else if (v > sec)  { sec = v; si = e; }
    }
    const float ew  = __expf(sec - best);
    const float inv = 1.0f / (1.0f + ew);
    const float wb  = inv, wsc = ew * inv;
    int emin, emax; float wmin, wmax;
    if (bi < si) { emin = bi; wmin = wb;  emax = si; wmax = wsc; }
    else         { emin = si; wmin = wsc; emax = bi; wmax = wb;  }
    const int pid = emin * 8 + emax;

    // ---- direct scatter: LDS-aggregated reservation into capacity buckets ----
    const int p = atomicAdd(&lc[pid], 1);
    __syncthreads();
    if (tid < 64) { lbase[tid] = lc[tid] ? atomicAdd(&cur[tid], (unsigned int)lc[tid]) : 0u; }
    __syncthreads();
    const size_t q = (size_t)pid * CAP + lbase[pid] + (unsigned int)p;
    perm[q] = (unsigned int)t;
    wps[q]  = make_float2(wmin, wmax);
}

// ---------------- pair GEMM (R13 structure) + copier tail ----------------
// M=128, 4 waves, dbuf depth-1, 51KB LDS -> 3 blk/CU. SINGLE CHANGE vs R13:
// out-stores are REGULAR stores (L2-acked, ~200cy) instead of non-temporal
// (HBM-acked, ~1-4us). The in-loop vmcnt(2) waits st(ph-1); with L2 ack that
// wait is cheap. Copier tail keeps NT (no waits there).
__launch_bounds__(256, 3)
__global__ void moe_gemm_kernel(const float* __restrict__ x,
                                const float* __restrict__ lat,
                                const unsigned short* __restrict__ Bpk,
                                const float* __restrict__ bias,
                                const float* __restrict__ biasl,
                                const unsigned int* __restrict__ c,   // 64 counts
                                const unsigned int* __restrict__ perm,
                                const float2* __restrict__ wps,
                                float* __restrict__ out,
                                float* __restrict__ lat_out)
{
    __shared__ __align__(16) unsigned short sB[2][2 * PH_STRIDE];   // 2 x 24KB
    __shared__ __align__(16) unsigned short sbias[6 * 256];         // 3KB bf16

    const unsigned int dd = blockIdx.x;
    const int tid  = threadIdx.x;

    if (dd >= GEMM_COMPUTE) {
        // ---- latents copier tail: 512 blocks x 32 f32x4/thread ----
        const int cb = (int)dd - GEMM_COMPUTE;
        const f32x4* src = (const f32x4*)lat + (size_t)cb * 8192;
        f32x4*       dst = (f32x4*)lat_out   + (size_t)cb * 8192;
#pragma unroll
        for (int i = 0; i < 32; ++i) {
            f32x4 v = __builtin_nontemporal_load(&src[tid + i * 256]);
            __builtin_nontemporal_store(v, &dst[tid + i * 256]);
        }
        return;
    }

    // XCD-chunked bijective swizzle (1056 = 8*132)
    const unsigned int bid = (dd & 7) * (GEMM_COMPUTE / 8) + (dd >> 3);
    const int lane = tid & 63;

    // ---- in-wave bucket lookup from counts (each wave redundantly) ----
    const unsigned int n_l  = c[lane];
    const unsigned int nt_l = (n_l + 127) >> 7;
    unsigned int ts = nt_l;
#pragma unroll
    for (int s = 1; s < 64; s <<= 1) {
        unsigned int tt = __shfl_up(ts, s);
        if (lane >= s) ts += tt;
    }
    const unsigned int texcl  = ts - nt_l;
    const unsigned int ntiles = __shfl(ts, 63);
    if (bid >= ntiles) return;                    // uniform exit before barriers
    const unsigned long long mk = __ballot(bid >= texcl);   // monotone prefix
    const int pid  = __popcll(mk) - 1;
    const int tile = (int)(bid - __shfl(texcl, pid));
    const unsigned int cn = __shfl(n_l, pid);
    const int emin = pid >> 3, emax = pid & 7;
    const int rows = min(128, (int)(cn - (unsigned int)tile * 128u));
    const unsigned int* permS = perm + (size_t)pid * CAP + (size_t)tile * 128u;
    const float2* wS = wps + (size_t)pid * CAP + (size_t)tile * 128u;

    const int w    = tid >> 6;           // 4 waves; wave owns rows w*32..w*32+31
    const int lrow = lane & 15;
    const int lgrp = lane >> 4;
    const int half = tid >> 7;           // 0: expert emin, 1: expert emax staging
    const int wh   = (tid >> 6) & 1;     // wave-within-half
    const int t7   = tid & 127;

    // ---- A gather -> registers (MFMA layout), f32 -> bf16, non-temporal ----
    const int r0 = w * 32 + lrow, r1 = r0 + 16;
    const int t0 = (int)permS[min(r0, rows - 1)];
    const int t1 = (int)permS[min(r1, rows - 1)];
    const float2 w0 = wS[min(r0, rows - 1)];
    const float2 w1 = wS[min(r1, rows - 1)];
    bf16x8 ax[2][4], al[2][4];
    {
        const float* x0 = x   + (size_t)t0 * INF_;
        const float* x1 = x   + (size_t)t1 * INF_;
        const float* l0 = lat + (size_t)t0 * LATF;
        const float* l1 = lat + (size_t)t1 * LATF;
#pragma unroll
        for (int ks = 0; ks < 4; ++ks) {
            const int kb = ks * 32 + lgrp * 8;
            ax[0][ks] = cvt8(__builtin_nontemporal_load((const f32x4*)(x0 + kb)),
                             __builtin_nontemporal_load((const f32x4*)(x0 + kb + 4)));
            ax[1][ks] = cvt8(__builtin_nontemporal_load((const f32x4*)(x1 + kb)),
                             __builtin_nontemporal_load((const f32x4*)(x1 + kb + 4)));
            al[0][ks] = cvt8(__builtin_nontemporal_load((const f32x4*)(l0 + kb)),
                             __builtin_nontemporal_load((const f32x4*)(l0 + kb + 4)));
            al[1][ks] = cvt8(__builtin_nontemporal_load((const f32x4*)(l1 + kb)),
                             __builtin_nontemporal_load((const f32x4*)(l1 + kb + 4)));
        }
    }

    const unsigned short* B0 = Bpk + (size_t)emin * EXP_STRIDE;
    const unsigned short* B1 = Bpk + (size_t)emax * EXP_STRIDE;
    const unsigned short* Bh = half ? B1 : B0;

    // ---- bias -> LDS as bf16: seg 0=b0h 1=b1h 2=b0s 3=b0f 4=b1s 5=b1f ----
    {
        const int i4 = (tid & 63) * 4;
        const int sg = tid >> 6;                 // 0..3
#pragma unroll
        for (int rep = 0; rep < 2; ++rep) {
            const int seg = sg + rep * 4;
            if (seg < 6) {
                const float* bsrc =
                    (seg == 0) ? bias  + emin * OUTF :
                    (seg == 1) ? bias  + emax * OUTF :
                    (seg == 2) ? biasl + emin * OUT2 :
                    (seg == 3) ? biasl + emin * OUT2 + 256 :
                    (seg == 4) ? biasl + emax * OUT2 :
                                 biasl + emax * OUT2 + 256;
                const f32x4 v = *(const f32x4*)(bsrc + i4);
                ushort4 u;
                u.x = bfbits(v.x); u.y = bfbits(v.y); u.z = bfbits(v.z); u.w = bfbits(v.w);
                *(ushort4*)&sbias[seg * 256 + i4] = u;
            }
        }
    }

    // stage phase ph's 24KB into buffer buf (6 loads/thread; 128 thr per expert half)
    auto STAGE = [&](int ph, int buf) {
        const unsigned short* src = Bh + (size_t)ph * PH_STRIDE + (size_t)t7 * 8;
        unsigned short* dst = &sB[buf][half * PH_STRIDE + wh * 512];
#pragma unroll
        for (int r = 0; r < 6; ++r)
            GLOAD_LDS16(src + r * 1024, dst + r * 1024);
    };

    f32x4 acc[2][3][2];   // [expert][mat][mf]; zero-init, bias added in epilogue
    auto COMPUTE = [&](int buf) {
#pragma unroll
        for (int ex = 0; ex < 2; ++ex)
#pragma unroll
            for (int m = 0; m < 3; ++m)
#pragma unroll
                for (int mf = 0; mf < 2; ++mf) acc[ex][m][mf] = (f32x4)0.0f;
#pragma unroll
        for (int ex = 0; ex < 2; ++ex) {
#pragma unroll
            for (int m = 0; m < 3; ++m) {
                bf16x8 bb[4];
#pragma unroll
                for (int ks = 0; ks < 4; ++ks)
                    bb[ks] = *(const bf16x8*)&sB[buf][ex * PH_STRIDE + (m * 4 + ks) * 512 + lane * 8];
#pragma unroll
                for (int ks = 0; ks < 4; ++ks) {
#pragma unroll
                    for (int mf = 0; mf < 2; ++mf) {
                        const bf16x8 a = (m == 0) ? ax[mf][ks] : al[mf][ks];
                        // swapped operands -> transposed C: row=outcol, col=token
                        acc[ex][m][mf] = __builtin_amdgcn_mfma_f32_16x16x32_bf16(bb[ks], a, acc[ex][m][mf], 0, 0, 0);
                    }
                }
            }
        }
    };

    auto EPILOGUE = [&](int ph, bool guard) {
        const int cb = ph * 16 + lgrp * 4;
        const f32x4 b0h = bload(&sbias[0 * 256 + cb]);
        const f32x4 b1h = bload(&sbias[1 * 256 + cb]);
        const f32x4 b0s = bload(&sbias[2 * 256 + cb]);
        const f32x4 b0f = bload(&sbias[3 * 256 + cb]);
        const f32x4 b1s = bload(&sbias[4 * 256 + cb]);
        const f32x4 b1f = bload(&sbias[5 * 256 + cb]);
#pragma unroll
        for (int mf = 0; mf < 2; ++mf) {
            const int  rr  = mf ? r1 : r0;
            if (guard && rr >= rows) continue;
            const int  tok = mf ? t1 : t0;
            const float wmn = mf ? w1.x : w0.x;
            const float wmx = mf ? w1.y : w0.y;
            f32x4 v;
#pragma unroll
            for (int j = 0; j < 4; ++j) {
                const float h0 = acc[0][0][mf][j] + b0h[j];
                const float s0 = acc[0][1][mf][j] + b0s[j];
                const float f0 = acc[0][2][mf][j] + b0f[j];
                const float h1 = acc[1][0][mf][j] + b1h[j];
                const float s1 = acc[1][1][mf][j] + b1s[j];
                const float f1 = acc[1][2][mf][j] + b1f[j];
                v[j] = wmn * __sinf(OMEGA_ * h0 * s0 + f0)
                     + wmx * __sinf(OMEGA_ * h1 * s1 + f1);
            }
            // REGULAR store (L2-acked) -- the single change vs R13
            *(f32x4*)(out + (size_t)tok * OUTF + cb) = v;
        }
    };

    // ---- prologue: bias ds_writes + S0; drain both counters, barrier ----
    STAGE(0, 0);
    asm volatile("s_waitcnt vmcnt(0) lgkmcnt(0)" ::: "memory");
    __builtin_amdgcn_s_barrier();
    __builtin_amdgcn_sched_barrier(0);

    if (rows == 128) {
        // ---- fast path: depth-1 dbuf; this-phase stores exempt from vmcnt ----
#pragma unroll 1
        for (int ph = 0; ph < 16; ++ph) {
            const int buf = ph & 1;
            if (ph < 15) STAGE(ph + 1, buf ^ 1);
            COMPUTE(buf);
            EPILOGUE(ph, false);
            __builtin_amdgcn_sched_barrier(0);
            if (ph < 15) {
                // queue: [st(ph-1)2, S(ph+1)6, st(ph)2]; wait S(ph+1)+st(ph-1)
                asm volatile("s_waitcnt vmcnt(2)" ::: "memory");
                __builtin_amdgcn_s_barrier();
                __builtin_amdgcn_sched_barrier(0);
            }
        }
    } else {
        // ---- slow path (partial tile, <=27 tiles): full drain per phase ----
#pragma unroll 1
        for (int ph = 0; ph < 16; ++ph) {
            const int buf = ph & 1;
            if (ph > 0) {
                STAGE(ph, buf);
                asm volatile("s_waitcnt vmcnt(0)" ::: "memory");
                __builtin_amdgcn_s_barrier();
                __builtin_amdgcn_sched_barrier(0);
            }
            COMPUTE(buf);
            EPILOGUE(ph, true);
            __builtin_amdgcn_s_barrier();
            __builtin_amdgcn_sched_barrier(0);
        }
    }
}

extern "C" void kernel_launch(void* const* d_in, const int* in_sizes, int n_in,
                              void* d_out, int out_size, void* d_ws, size_t ws_size,
                              hipStream_t stream)
{
    const float* x   = (const float*)d_in[0];
    const float* lat = (const float*)d_in[1];
    const float* gw  = (const float*)d_in[2];
    const float* gb  = (const float*)d_in[3];
    const float* W   = (const float*)d_in[4];
    const float* b   = (const float*)d_in[5];
    const float* Wl  = (const float*)d_in[6];
    const float* bl  = (const float*)d_in[7];
    float* out = (float*)d_out;
    const int N = in_sizes[0] / INF_;   // 131072

    char* ws = (char*)d_ws;
    unsigned int*   cur  = (unsigned int*)ws;                         // 64 cursors (=counts)
    unsigned short* Bpk  = (unsigned short*)(ws + 4096);              // 1.5MB
    unsigned int*   perm = (unsigned int*)(ws + (4096 + 2 * (size_t)EXP_STRIDE * NEXP + 4096));
    float2*         wps  = (float2*)((char*)perm + (size_t)64 * CAP * sizeof(unsigned int));

    (void)hipMemsetAsync(cur, 0, 256, stream);      // zero cursors only

    const int nGate = N / 256;                      // 512
    prep_kernel<<<dim3(nGate + PACK_THREADS / 256), 256, 0, stream>>>(
        x, gw, gb, W, Wl, cur, perm, wps, Bpk, nGate);

    moe_gemm_kernel<<<dim3(GEMM_GRID), 256, 0, stream>>>(
        x, lat, Bpk, b, bl, cur, perm, wps, out, out + (size_t)N * OUTF);
}